// Round 5
// baseline (172.361 us; speedup 1.0000x reference)
//
#include <hip/hip_runtime.h>
#include <stdint.h>

// Problem dims: x(4,2048,512) W1(512,1024) b1(1024) Wq(1024,1024) A=16 — fp32 in, fp32 out
constexpr int BATCH = 4;
constexpr int SEQ   = 2048;
constexpr int DIN   = 512;
constexpr int DH    = 1024;
constexpr int BS    = BATCH * SEQ;  // 8192
constexpr int AP    = 32;           // attn positions per block
constexpr int AW    = 64;           // attn window rows (AP + 2*16)

typedef float  floatx4 __attribute__((ext_vector_type(4)));
typedef short  bf16x8  __attribute__((ext_vector_type(8)));

static __device__ __forceinline__ unsigned short f2bf(float f) {
  union { float f; unsigned u; } v; v.f = f;
  unsigned r = (v.u + 0x7fffu + ((v.u >> 16) & 1u)) >> 16;  // RNE
  return (unsigned short)r;
}

// async global->LDS, 16B per lane; LDS dest is wave-uniform base + lane*16
static __device__ __forceinline__ void gld_lds16(const unsigned short* g, const short* l) {
  typedef const __attribute__((address_space(1))) void* gvp;
  typedef __attribute__((address_space(3))) void* lvp;
  __builtin_amdgcn_global_load_lds((gvp)(uintptr_t)g, (lvp)(unsigned)(uintptr_t)l, 16, 0, 0);
}

// ---------------- elementwise fp32 -> bf16 ----------------
__global__ __launch_bounds__(256) void to_bf16_k(const float* __restrict__ in,
                                                 unsigned short* __restrict__ out, int n) {
  int i = (blockIdx.x * 256 + threadIdx.x) * 4;
  if (i < n) {
    float4 v = *(const float4*)(in + i);
    ushort4 o;
    o.x = f2bf(v.x); o.y = f2bf(v.y); o.z = f2bf(v.z); o.w = f2bf(v.w);
    *(ushort4*)(out + i) = o;
  }
}

// ---------------- transpose fp32 (R x C) -> bf16 (C x R) ----------------
__global__ __launch_bounds__(256) void transpose_bf16_k(const float* __restrict__ in,
                                                        unsigned short* __restrict__ out,
                                                        int R, int C) {
  __shared__ float t[32][33];
  int c0 = blockIdx.x * 32, r0 = blockIdx.y * 32;
  int tx = threadIdx.x & 31, ty = threadIdx.x >> 5;  // 32 x 8
  for (int i = ty; i < 32; i += 8) t[i][tx] = in[(size_t)(r0 + i) * C + c0 + tx];
  __syncthreads();
  for (int i = ty; i < 32; i += 8) out[(size_t)(c0 + i) * R + r0 + tx] = f2bf(t[tx][i]);
}

// ---------------- transpose bf16 [BS][DH] -> [DH][BS], 64x64 tiles ----------------
__global__ __launch_bounds__(256) void transpose_hb_k(const unsigned short* __restrict__ in,
                                                      unsigned short* __restrict__ out) {
  __shared__ __align__(16) unsigned short t[64][80];  // stride 160B: 16B-aligned rows
  const int tid = threadIdx.x;
  const int r0 = blockIdx.x * 64;  // BS dim
  const int c0 = blockIdx.y * 64;  // DH dim
  const int tr = tid >> 2, tc = (tid & 3) * 16;
  const uint4* src = (const uint4*)(in + (size_t)(r0 + tr) * DH + c0 + tc);
  uint4 v0 = src[0], v1 = src[1];
  *(uint4*)&t[tr][tc]     = v0;
  *(uint4*)&t[tr][tc + 8] = v1;
  __syncthreads();
  // out[(c0+tr)*BS + r0+tc+e] = t[tc+e][tr]
  __align__(16) unsigned short vals[16];
  #pragma unroll
  for (int e = 0; e < 16; e++) vals[e] = t[tc + e][tr];
  uint4* dst = (uint4*)(out + (size_t)(c0 + tr) * BS + r0 + tc);
  dst[0] = ((uint4*)vals)[0];
  dst[1] = ((uint4*)vals)[1];
}

// ---------------- bf16 MFMA GEMM: C[MxN] = A[MxK] * B[KxN], B given as B^T (NxK) ---------
// 128x128 tile, BK=32, 256 threads (4 waves, 2x2 of 64x64), 4x4 16x16x32 MFMAs per wave.
// Staging via global_load_lds dwordx4 (m97 pattern): wave wv covers rows wv*32..wv*32+31
// of As and Bs; issue q covers 16 rows = 1024B contiguous LDS, lane i -> base + i*16.
template <bool RELU>
__global__ __launch_bounds__(256) void gemm_bt(const unsigned short* __restrict__ Ab,
                                               const unsigned short* __restrict__ Bt,
                                               const float* __restrict__ bias,
                                               unsigned short* __restrict__ outB,
                                               int M, int N, int K) {
  __shared__ __align__(16) short As[128 * 32];
  __shared__ __align__(16) short Bs[128 * 32];
  const int tid  = threadIdx.x;
  const int m0   = blockIdx.y * 128, n0 = blockIdx.x * 128;
  const int wv   = tid >> 6, lane = tid & 63;
  const int wm   = (wv >> 1) * 64, wn = (wv & 1) * 64;
  const int l16  = lane & 15, quad = lane >> 4;

  // staging addressing
  const int ra = lane >> 2;        // 0..15 (row within 16-row issue)
  const int ca = (lane & 3) * 8;   // element col 0/8/16/24
  const unsigned short* gA0 = Ab + (size_t)(m0 + wv * 32 + ra) * K + ca;
  const unsigned short* gA1 = Ab + (size_t)(m0 + wv * 32 + 16 + ra) * K + ca;
  const unsigned short* gB0 = Bt + (size_t)(n0 + wv * 32 + ra) * K + ca;
  const unsigned short* gB1 = Bt + (size_t)(n0 + wv * 32 + 16 + ra) * K + ca;
  const short* lA0 = &As[wv * 1024];
  const short* lA1 = &As[wv * 1024 + 512];
  const short* lB0 = &Bs[wv * 1024];
  const short* lB1 = &Bs[wv * 1024 + 512];

  floatx4 acc[4][4];
  for (int i = 0; i < 4; i++)
    for (int j = 0; j < 4; j++) acc[i][j] = {0.f, 0.f, 0.f, 0.f};

  const int ksteps = K >> 5;
  for (int ks = 0; ks < ksteps; ++ks) {
    __syncthreads();  // prev iter's LDS reads done before overwrite
    gld_lds16(gA0, lA0); gld_lds16(gA1, lA1);
    gld_lds16(gB0, lB0); gld_lds16(gB1, lB1);
    gA0 += 32; gA1 += 32; gB0 += 32; gB1 += 32;
    __syncthreads();  // drains vmcnt(0) before s_barrier -> LDS writes visible
    bf16x8 af[4], bfr[4];
    for (int i = 0; i < 4; i++)
      af[i] = *(const bf16x8*)&As[(wm + i * 16 + l16) * 32 + quad * 8];
    for (int j = 0; j < 4; j++)
      bfr[j] = *(const bf16x8*)&Bs[(wn + j * 16 + l16) * 32 + quad * 8];
    for (int i = 0; i < 4; i++)
      for (int j = 0; j < 4; j++)
        acc[i][j] = __builtin_amdgcn_mfma_f32_16x16x32_bf16(af[i], bfr[j], acc[i][j], 0, 0, 0);
  }

  // epilogue: C row = m0+wm+i*16+quad*4+r, col = n0+wn+j*16+l16 (m89-verified C/D layout)
  for (int j = 0; j < 4; j++) {
    const int col = n0 + wn + j * 16 + l16;
    const float bv = RELU ? bias[col] : 0.f;
    for (int i = 0; i < 4; i++) {
      const int rowb = m0 + wm + i * 16 + quad * 4;
      for (int r = 0; r < 4; r++) {
        float v = acc[i][j][r] + bv;
        if (RELU) v = fmaxf(v, 0.f);
        outB[(size_t)(rowb + r) * N + col] = f2bf(v);
      }
    }
  }
}

// ---------------- MFMA banded attention ----------------
// Block: 512 threads (8 waves), AP=32 positions. Window AW=64 rows (jj = 0..63,
// seq j = s0-16+jj). scores[s][w] = q[s].h[s+16-w]/32; jj = row + (32-w).
// OOB rows staged as zeros -> score 0, participates in softmax (matches reference pad).
__global__ __launch_bounds__(512) void attn_mfma_k(const unsigned short* __restrict__ hb,
                                                   const unsigned short* __restrict__ hbT,
                                                   const unsigned short* __restrict__ qb,
                                                   float* __restrict__ out) {
  __shared__ __align__(16) short Qs[32 * 72];   // q tile, BK=64, stride 72
  __shared__ __align__(16) short Hs[64 * 72];   // h window tile (row-major, k contig)
  __shared__ __align__(16) short Ps[32 * 72];   // softmax weights (A-frag layout)
  __shared__ __align__(16) short Ht[128 * 72];  // h window^T chunk for PV
  __shared__ float Sf[32 * 64];                 // raw scores

  const int tid  = threadIdx.x;
  const int wave = tid >> 6, lane = tid & 63;
  const int l16  = lane & 15, quad = lane >> 4;
  const int p0   = blockIdx.x * AP;
  const int s0   = p0 & (SEQ - 1);

  // zero P (invalid band entries must be 0)
  for (int i = tid; i < 32 * 72 / 2; i += 512) ((unsigned*)Ps)[i] = 0;

  // ---------- QK: S[32x64] = q[32xDH] @ Hwin[64xDH]^T ----------
  const int mtile = wave >> 2;       // 0..1
  const int ntile = wave & 3;        // 0..3
  const bool isQ = tid < 128;
  const bool isH = (tid >= 128) && (tid < 384);
  const int sq = tid & 3;
  int srow = isQ ? (tid >> 2) : ((tid - 128) >> 2);
  bool ldv = false;
  const uint4* gsrc = nullptr;
  short* ldst = nullptr;
  if (isQ) {
    ldv = true;
    gsrc = (const uint4*)(qb + (size_t)(p0 + srow) * DH + sq * 16);
    ldst = &Qs[srow * 72 + sq * 16];
  } else if (isH) {
    const int hj = s0 - 16 + srow;
    ldv = (hj >= 0) && (hj < SEQ);
    gsrc = (const uint4*)(hb + (long long)(p0 - 16 + srow) * DH + sq * 16);
    ldst = &Hs[srow * 72 + sq * 16];
  }

  floatx4 acc = {0.f, 0.f, 0.f, 0.f};
  for (int ks = 0; ks < DH / 64; ++ks) {
    uint4 r0 = {0, 0, 0, 0}, r1 = {0, 0, 0, 0};
    if (ldv) { r0 = gsrc[0]; r1 = gsrc[1]; gsrc += 8; }
    __syncthreads();
    if (isQ || isH) { ((uint4*)ldst)[0] = r0; ((uint4*)ldst)[1] = r1; }
    __syncthreads();
    bf16x8 a0 = *(const bf16x8*)&Qs[(mtile * 16 + l16) * 72 + quad * 8];
    bf16x8 a1 = *(const bf16x8*)&Qs[(mtile * 16 + l16) * 72 + 32 + quad * 8];
    bf16x8 b0 = *(const bf16x8*)&Hs[(ntile * 16 + l16) * 72 + quad * 8];
    bf16x8 b1 = *(const bf16x8*)&Hs[(ntile * 16 + l16) * 72 + 32 + quad * 8];
    acc = __builtin_amdgcn_mfma_f32_16x16x32_bf16(a0, b0, acc, 0, 0, 0);
    acc = __builtin_amdgcn_mfma_f32_16x16x32_bf16(a1, b1, acc, 0, 0, 0);
  }
  // write scores (scaled by 1/sqrt(DH)=1/32)
  for (int r = 0; r < 4; r++)
    Sf[(mtile * 16 + quad * 4 + r) * 64 + ntile * 16 + l16] = acc[r] * (1.f / 32.f);
  __syncthreads();

  // ---------- softmax over the 33 band entries jj = row..row+32 ----------
  {
    const int row = tid >> 4, k = tid & 15;  // 16 threads per row
    const float v0 = Sf[row * 64 + row + k];
    const float v1 = Sf[row * 64 + row + k + 16];
    const float v2 = (k == 0) ? Sf[row * 64 + row + 32] : -1e30f;
    float mx = fmaxf(v0, fmaxf(v1, v2));
    for (int off = 1; off < 16; off <<= 1) mx = fmaxf(mx, __shfl_xor(mx, off, 64));
    const float e0 = __expf(v0 - mx), e1 = __expf(v1 - mx);
    const float e2 = (k == 0) ? __expf(v2 - mx) : 0.f;
    float sum = e0 + e1 + e2;
    for (int off = 1; off < 16; off <<= 1) sum += __shfl_xor(sum, off, 64);
    const float inv = 1.f / sum;
    Ps[row * 72 + row + k] = f2bf(e0 * inv);
    Ps[row * 72 + row + k + 16] = f2bf(e1 * inv);
    if (k == 0) Ps[row * 72 + row + 32] = f2bf(e2 * inv);
  }
  __syncthreads();

  // ---------- PV: out[32xDH] = P[32x64] @ Hwin[64xDH], chunked over DH ----------
  const bf16x8 pa0 = *(const bf16x8*)&Ps[(mtile * 16 + l16) * 72 + quad * 8];
  const bf16x8 pa1 = *(const bf16x8*)&Ps[(mtile * 16 + l16) * 72 + 32 + quad * 8];

  int lo = 16 - s0; if (lo < 0) lo = 0;             // valid window-col range [lo,hi)
  int hi = SEQ + 16 - s0; if (hi > AW) hi = AW;
  const bool interior = (lo == 0) && (hi == AW);
  const int hn = tid >> 2;  // 0..127: Ht row (dh)
  const int ntp = (wave & 3) * 2;

  for (int c = 0; c < DH / 128; ++c) {
    const int nc = c * 128;
    const unsigned short* hp = hbT + ((long long)(nc + hn) * BS + p0 - 16 + sq * 16);
    uint4 r0 = ((const uint4*)hp)[0], r1 = ((const uint4*)hp)[1];
    if (!interior) {
      unsigned short vals[16];
      ((uint4*)vals)[0] = r0; ((uint4*)vals)[1] = r1;
      #pragma unroll
      for (int e = 0; e < 16; e++) {
        const int k = sq * 16 + e;
        if (k < lo || k >= hi) vals[e] = 0;
      }
      r0 = ((uint4*)vals)[0]; r1 = ((uint4*)vals)[1];
    }
    __syncthreads();
    ((uint4*)&Ht[hn * 72 + sq * 16])[0] = r0;
    ((uint4*)&Ht[hn * 72 + sq * 16])[1] = r1;
    __syncthreads();
    floatx4 acc2[2] = {{0.f, 0.f, 0.f, 0.f}, {0.f, 0.f, 0.f, 0.f}};
    for (int t = 0; t < 2; t++) {
      const int nt = ntp + t;
      bf16x8 b0 = *(const bf16x8*)&Ht[(nt * 16 + l16) * 72 + quad * 8];
      bf16x8 b1 = *(const bf16x8*)&Ht[(nt * 16 + l16) * 72 + 32 + quad * 8];
      acc2[t] = __builtin_amdgcn_mfma_f32_16x16x32_bf16(pa0, b0, acc2[t], 0, 0, 0);
      acc2[t] = __builtin_amdgcn_mfma_f32_16x16x32_bf16(pa1, b1, acc2[t], 0, 0, 0);
    }
    for (int t = 0; t < 2; t++) {
      const int col = nc + (ntp + t) * 16 + l16;
      for (int r = 0; r < 4; r++)
        out[(size_t)(p0 + mtile * 16 + quad * 4 + r) * DH + col] = acc2[t][r];
    }
  }
}

extern "C" void kernel_launch(void* const* d_in, const int* in_sizes, int n_in,
                              void* d_out, int out_size, void* d_ws, size_t ws_size,
                              hipStream_t stream) {
  const float* x  = (const float*)d_in[0];
  const float* W1 = (const float*)d_in[1];
  const float* b1 = (const float*)d_in[2];
  const float* Wq = (const float*)d_in[3];

  // workspace layout (59 MB total)
  char* w = (char*)d_ws;
  unsigned short* xb  = (unsigned short*)(w);                  // 8 MB  x bf16
  unsigned short* w1t = (unsigned short*)(w + (8ull  << 20));  // 1 MB  W1^T bf16
  unsigned short* wqt = (unsigned short*)(w + (9ull  << 20));  // 2 MB  Wq^T bf16
  unsigned short* hb  = (unsigned short*)(w + (11ull << 20));  // 16 MB h bf16 row-major
  unsigned short* hbT = (unsigned short*)(w + (27ull << 20));  // 16 MB h bf16 transposed [DH][BS]
  unsigned short* qb  = (unsigned short*)(w + (43ull << 20));  // 16 MB q bf16 row-major

  to_bf16_k<<<(BS * DIN) / (256 * 4), 256, 0, stream>>>(x, xb, BS * DIN);
  transpose_bf16_k<<<dim3(DH / 32, DIN / 32), 256, 0, stream>>>(W1, w1t, DIN, DH);
  transpose_bf16_k<<<dim3(DH / 32, DH / 32), 256, 0, stream>>>(Wq, wqt, DH, DH);

  // h = relu(x @ W1 + b1)
  gemm_bt<true><<<dim3(DH / 128, BS / 128), 256, 0, stream>>>(xb, w1t, b1, hb, BS, DH, DIN);
  // hbT = h^T (dedicated coalesced transpose; removed from GEMM1's epilogue)
  transpose_hb_k<<<dim3(BS / 64, DH / 64), 256, 0, stream>>>(hb, hbT);
  // q = h @ Wq
  gemm_bt<false><<<dim3(DH / 128, BS / 128), 256, 0, stream>>>(hb, wqt, nullptr, qb, BS, DH, DH);

  attn_mfma_k<<<BS / AP, 512, 0, stream>>>(hb, hbT, qb, (float*)d_out);
}